// Round 1
// baseline (201.312 us; speedup 1.0000x reference)
//
#include <hip/hip_runtime.h>
#include <stdint.h>

// ---------------- problem constants (from reference) ----------------
constexpr int NN   = 20000;          // N_NODES
constexpr int DD   = 8;              // D
constexpr int ND   = NN * DD;        // 160000 block-rows
constexpr uint32_t HBITS = 20;
constexpr uint32_t HSIZE = 1u << HBITS;   // 1,048,576 slots for 500k keys
constexpr uint32_t HMASK = HSIZE - 1;

__device__ __forceinline__ uint32_t hkey(uint32_t k) {
    k *= 2654435761u;
    return k ^ (k >> 15);
}

// ---------------- init: hash sentinels + deg=1 (identity contribution) ----
__global__ void k_init(int* __restrict__ keys, int* __restrict__ vals,
                       float* __restrict__ deg) {
    uint32_t i = blockIdx.x * blockDim.x + threadIdx.x;
    if (i < HSIZE) { keys[i] = -1; vals[i] = 0x7FFFFFFF; }
    if (i < (uint32_t)ND) deg[i] = 1.0f;
}

// ---------------- insert edges: key = row*NN+col, val = min edge idx ------
__global__ void k_insert(const int* __restrict__ row, const int* __restrict__ col,
                         int* __restrict__ keys, int* __restrict__ vals, int E) {
    int e = blockIdx.x * blockDim.x + threadIdx.x;
    if (e >= E) return;
    int key = row[e] * NN + col[e];
    uint32_t s = hkey((uint32_t)key) & HMASK;
    while (true) {
        int prev = atomicCAS(&keys[s], -1, key);
        if (prev == -1 || prev == key) { atomicMin(&vals[s], e); return; }
        s = (s + 1) & HMASK;
    }
}

// ---------------- fused: reverse lookup + P = F_e^T @ F_rev + deg accum ---
// 256 threads per block, 32 edges per block (8 threads / edge).
// LDS stride 68 floats: pad 4 keeps float4 alignment, kills 8-way conflicts.
__global__ void k_p(const float* __restrict__ F,
                    const int* __restrict__ row, const int* __restrict__ col,
                    const int* __restrict__ keys, const int* __restrict__ vals,
                    float* __restrict__ outP, float* __restrict__ deg, int E) {
    __shared__ float fa[32 * 68];
    __shared__ float fb[32 * 68];
    __shared__ int   s_rev[32];
    __shared__ int   s_row[32];
    const int t  = threadIdx.x;
    const int e0 = blockIdx.x * 32;

    if (t < 32) {
        int e = e0 + t;
        if (e < E) {
            int r = row[e], c = col[e];
            s_row[t] = r;
            int key = c * NN + r;                 // reverse hash rh
            uint32_t s = hkey((uint32_t)key) & HMASK;
            int rv = e;                           // identity fallback
            while (true) {
                int k = keys[s];
                if (k == key) { rv = vals[s]; break; }
                if (k == -1) break;
                s = (s + 1) & HMASK;
            }
            s_rev[t] = rv;
        }
    }
    __syncthreads();

    // stage 32 edges of F (sequential) and F[rev] (gather, 256B blocks)
    const float4* F4 = (const float4*)F;
    #pragma unroll
    for (int p = 0; p < 2; ++p) {
        int f   = t + p * 256;                    // 0..511 float4s
        int es  = f >> 4;                         // edge within block
        int off = (f & 15) << 2;                  // float offset in edge
        int ge  = e0 + es;
        if (ge < E) {
            float4 va = F4[(size_t)ge * 16 + (f & 15)];
            *(float4*)&fa[es * 68 + off] = va;
            float4 vb = F4[(size_t)s_rev[es] * 16 + (f & 15)];
            *(float4*)&fb[es * 68 + off] = vb;
        }
    }
    __syncthreads();

    const int es = t >> 3;                        // edge sub-index 0..31
    const int i  = t & 7;                         // P row
    const int e  = e0 + es;
    if (e >= E) return;

    const float* fav = &fa[es * 68];
    const float* fbv = &fb[es * 68];
    float acc0 = 0.f, acc1 = 0.f, acc2 = 0.f, acc3 = 0.f;
    float acc4 = 0.f, acc5 = 0.f, acc6 = 0.f, acc7 = 0.f;
    #pragma unroll
    for (int j = 0; j < 8; ++j) {
        float  a  = fav[j * 8 + i];               // F[e][j][i] (column read)
        float4 b0 = *(const float4*)&fbv[j * 8];
        float4 b1 = *(const float4*)&fbv[j * 8 + 4];
        acc0 = fmaf(a, b0.x, acc0);  acc1 = fmaf(a, b0.y, acc1);
        acc2 = fmaf(a, b0.z, acc2);  acc3 = fmaf(a, b0.w, acc3);
        acc4 = fmaf(a, b1.x, acc4);  acc5 = fmaf(a, b1.y, acc5);
        acc6 = fmaf(a, b1.z, acc6);  acc7 = fmaf(a, b1.w, acc7);
    }
    float rs = fabsf(acc0) + fabsf(acc1) + fabsf(acc2) + fabsf(acc3)
             + fabsf(acc4) + fabsf(acc5) + fabsf(acc6) + fabsf(acc7);
    atomicAdd(&deg[s_row[es] * DD + i], rs);

    size_t ob = (size_t)e * 64 + i * 8;
    *(float4*)&outP[ob]     = make_float4(acc0, acc1, acc2, acc3);
    *(float4*)&outP[ob + 4] = make_float4(acc4, acc5, acc6, acc7);
}

// ---------------- dinv = deg^-0.5 (deg >= 1 always) -----------------------
__global__ void k_dinv(const float* __restrict__ deg, float* __restrict__ dinv) {
    int r = blockIdx.x * blockDim.x + threadIdx.x;
    if (r < ND) dinv[r] = 1.0f / sqrtf(deg[r]);
}

// ---------------- normalize off-diag in place + write diagonal blocks -----
// one float4 per thread over the whole output ((E+NN)*16 float4s)
__global__ void k_norm(const int* __restrict__ row, const int* __restrict__ col,
                       const float* __restrict__ dinv, float* __restrict__ out,
                       int E) {
    int idx = blockIdx.x * blockDim.x + threadIdx.x;
    int offEnd = E * 16;
    if (idx < offEnd) {
        int e   = idx >> 4;
        int rem = idx & 15;
        int i   = rem >> 1;
        int kb  = (rem & 1) * 4;
        float4 v = ((float4*)out)[idx];
        float dr = dinv[row[e] * DD + i];
        int cb   = col[e] * DD + kb;
        v.x *= dr * dinv[cb];
        v.y *= dr * dinv[cb + 1];
        v.z *= dr * dinv[cb + 2];
        v.w *= dr * dinv[cb + 3];
        ((float4*)out)[idx] = v;
    } else {
        int idx2 = idx - offEnd;
        if (idx2 < NN * 16) {
            int vtx = idx2 >> 4;
            int rem = idx2 & 15;
            int i   = rem >> 1;
            int kb  = (rem & 1) * 4;
            float dv = dinv[vtx * DD + i];
            float dd = dv * dv;
            float4 o = make_float4(0.f, 0.f, 0.f, 0.f);
            int lk = i - kb;                       // diagonal hits when k==i
            if (lk >= 0 && lk < 4) (&o.x)[lk] = dd;
            ((float4*)out)[idx] = o;
        }
    }
}

extern "C" void kernel_launch(void* const* d_in, const int* in_sizes, int n_in,
                              void* d_out, int out_size, void* d_ws, size_t ws_size,
                              hipStream_t stream) {
    const float* F  = (const float*)d_in[0];
    const int*   ei = (const int*)d_in[1];
    const int E = in_sizes[1] / 2;
    const int* row = ei;
    const int* col = ei + E;

    // workspace layout (~9.7 MB)
    int*   keys = (int*)d_ws;
    int*   vals = keys + HSIZE;
    float* deg  = (float*)(vals + HSIZE);
    float* dinv = deg + ND;
    float* out  = (float*)d_out;

    k_init<<<(HSIZE + 255) / 256, 256, 0, stream>>>(keys, vals, deg);
    k_insert<<<(E + 255) / 256, 256, 0, stream>>>(row, col, keys, vals, E);
    k_p<<<(E + 31) / 32, 256, 0, stream>>>(F, row, col, keys, vals, out, deg, E);
    k_dinv<<<(ND + 255) / 256, 256, 0, stream>>>(deg, dinv);
    int totalV4 = (E + NN) * 16;
    k_norm<<<(totalV4 + 255) / 256, 256, 0, stream>>>(row, col, dinv, out, E);
}

// Round 3
// 200.450 us; speedup vs baseline: 1.0043x; 1.0043x over previous
//
#include <hip/hip_runtime.h>
#include <stdint.h>

// ---------------- problem constants (from reference) ----------------
constexpr int NN   = 20000;          // N_NODES
constexpr int DD   = 8;              // D
constexpr int ND   = NN * DD;        // 160000 block-rows
constexpr uint32_t HBITS = 20;
constexpr uint32_t HSIZE = 1u << HBITS;   // 1,048,576 slots for 500k keys
constexpr uint32_t HMASK = HSIZE - 1;

typedef float v4f __attribute__((ext_vector_type(4)));

__device__ __forceinline__ uint32_t hkey(uint32_t k) {
    k *= 2654435761u;
    return k ^ (k >> 15);
}

// ---------------- init: hash sentinels + deg=1 (identity contribution) ----
__global__ void k_init(int* __restrict__ keys, int* __restrict__ vals,
                       float* __restrict__ deg) {
    uint32_t i = blockIdx.x * blockDim.x + threadIdx.x;
    if (i < HSIZE) { keys[i] = -1; vals[i] = 0x7FFFFFFF; }
    if (i < (uint32_t)ND) deg[i] = 1.0f;
}

// ---------------- insert edges: key = row*NN+col, val = min edge idx ------
__global__ void k_insert(const int* __restrict__ row, const int* __restrict__ col,
                         int* __restrict__ keys, int* __restrict__ vals, int E) {
    int e = blockIdx.x * blockDim.x + threadIdx.x;
    if (e >= E) return;
    int key = row[e] * NN + col[e];
    uint32_t s = hkey((uint32_t)key) & HMASK;
    while (true) {
        int prev = atomicCAS(&keys[s], -1, key);
        if (prev == -1 || prev == key) { atomicMin(&vals[s], e); return; }
        s = (s + 1) & HMASK;
    }
}

// ---------------- pass A: reverse lookup (stored) + deg accumulation ------
// 256 threads per block, 32 edges per block (8 threads / edge).
// Computes P but does NOT write it — only deg += rowsum(|P|). Writes rev[].
__global__ void k_deg(const float* __restrict__ F,
                      const int* __restrict__ row, const int* __restrict__ col,
                      const int* __restrict__ keys, const int* __restrict__ vals,
                      int* __restrict__ rev_out, float* __restrict__ deg, int E) {
    __shared__ float fa[32 * 68];
    __shared__ float fb[32 * 68];
    __shared__ int   s_rev[32];
    __shared__ int   s_row[32];
    const int t  = threadIdx.x;
    const int e0 = blockIdx.x * 32;

    if (t < 32) {
        int e = e0 + t;
        if (e < E) {
            int r = row[e], c = col[e];
            s_row[t] = r;
            int key = c * NN + r;                 // reverse hash rh
            uint32_t s = hkey((uint32_t)key) & HMASK;
            int rv = e;                           // identity fallback
            while (true) {
                int k = keys[s];
                if (k == key) { rv = vals[s]; break; }
                if (k == -1) break;
                s = (s + 1) & HMASK;
            }
            s_rev[t] = rv;
            rev_out[e] = rv;
        }
    }
    __syncthreads();

    const float4* F4 = (const float4*)F;
    #pragma unroll
    for (int p = 0; p < 2; ++p) {
        int f   = t + p * 256;                    // 0..511 float4s
        int es  = f >> 4;
        int off = (f & 15) << 2;
        int ge  = e0 + es;
        if (ge < E) {
            float4 va = F4[(size_t)ge * 16 + (f & 15)];
            *(float4*)&fa[es * 68 + off] = va;
            float4 vb = F4[(size_t)s_rev[es] * 16 + (f & 15)];
            *(float4*)&fb[es * 68 + off] = vb;
        }
    }
    __syncthreads();

    const int es = t >> 3;
    const int i  = t & 7;
    const int e  = e0 + es;
    if (e >= E) return;

    const float* fav = &fa[es * 68];
    const float* fbv = &fb[es * 68];
    float acc0 = 0.f, acc1 = 0.f, acc2 = 0.f, acc3 = 0.f;
    float acc4 = 0.f, acc5 = 0.f, acc6 = 0.f, acc7 = 0.f;
    #pragma unroll
    for (int j = 0; j < 8; ++j) {
        float  a  = fav[j * 8 + i];
        float4 b0 = *(const float4*)&fbv[j * 8];
        float4 b1 = *(const float4*)&fbv[j * 8 + 4];
        acc0 = fmaf(a, b0.x, acc0);  acc1 = fmaf(a, b0.y, acc1);
        acc2 = fmaf(a, b0.z, acc2);  acc3 = fmaf(a, b0.w, acc3);
        acc4 = fmaf(a, b1.x, acc4);  acc5 = fmaf(a, b1.y, acc5);
        acc6 = fmaf(a, b1.z, acc6);  acc7 = fmaf(a, b1.w, acc7);
    }
    float rs = fabsf(acc0) + fabsf(acc1) + fabsf(acc2) + fabsf(acc3)
             + fabsf(acc4) + fabsf(acc5) + fabsf(acc6) + fabsf(acc7);
    atomicAdd(&deg[s_row[es] * DD + i], rs);
}

// ---------------- dinv = deg^-0.5 (deg >= 1 always) -----------------------
__global__ void k_dinv(const float* __restrict__ deg, float* __restrict__ dinv) {
    int r = blockIdx.x * blockDim.x + threadIdx.x;
    if (r < ND) dinv[r] = 1.0f / sqrtf(deg[r]);
}

// ---------------- pass B: recompute P, write normalized (NT stores) -------
__global__ void k_pnorm(const float* __restrict__ F,
                        const int* __restrict__ row, const int* __restrict__ col,
                        const int* __restrict__ rev, const float* __restrict__ dinv,
                        float* __restrict__ out, int E) {
    __shared__ float fa[32 * 68];
    __shared__ float fb[32 * 68];
    __shared__ int   s_rev[32];
    __shared__ int   s_row[32];
    __shared__ int   s_col[32];
    const int t  = threadIdx.x;
    const int e0 = blockIdx.x * 32;

    if (t < 32) {
        int e = e0 + t;
        if (e < E) {
            s_row[t] = row[e];
            s_col[t] = col[e];
            s_rev[t] = rev[e];
        }
    }
    __syncthreads();

    const float4* F4 = (const float4*)F;
    #pragma unroll
    for (int p = 0; p < 2; ++p) {
        int f   = t + p * 256;
        int es  = f >> 4;
        int off = (f & 15) << 2;
        int ge  = e0 + es;
        if (ge < E) {
            float4 va = F4[(size_t)ge * 16 + (f & 15)];
            *(float4*)&fa[es * 68 + off] = va;
            float4 vb = F4[(size_t)s_rev[es] * 16 + (f & 15)];
            *(float4*)&fb[es * 68 + off] = vb;
        }
    }
    __syncthreads();

    const int es = t >> 3;
    const int i  = t & 7;
    const int e  = e0 + es;
    if (e >= E) return;

    const float* fav = &fa[es * 68];
    const float* fbv = &fb[es * 68];
    float acc0 = 0.f, acc1 = 0.f, acc2 = 0.f, acc3 = 0.f;
    float acc4 = 0.f, acc5 = 0.f, acc6 = 0.f, acc7 = 0.f;
    #pragma unroll
    for (int j = 0; j < 8; ++j) {
        float  a  = fav[j * 8 + i];
        float4 b0 = *(const float4*)&fbv[j * 8];
        float4 b1 = *(const float4*)&fbv[j * 8 + 4];
        acc0 = fmaf(a, b0.x, acc0);  acc1 = fmaf(a, b0.y, acc1);
        acc2 = fmaf(a, b0.z, acc2);  acc3 = fmaf(a, b0.w, acc3);
        acc4 = fmaf(a, b1.x, acc4);  acc5 = fmaf(a, b1.y, acc5);
        acc6 = fmaf(a, b1.z, acc6);  acc7 = fmaf(a, b1.w, acc7);
    }

    float dr = dinv[s_row[es] * DD + i];
    int   cb = s_col[es] * DD;
    float4 dc0 = *(const float4*)&dinv[cb];
    float4 dc1 = *(const float4*)&dinv[cb + 4];

    size_t ob = (size_t)e * 64 + i * 8;
    v4f o0 = { acc0 * dr * dc0.x, acc1 * dr * dc0.y,
               acc2 * dr * dc0.z, acc3 * dr * dc0.w };
    v4f o1 = { acc4 * dr * dc1.x, acc5 * dr * dc1.y,
               acc6 * dr * dc1.z, acc7 * dr * dc1.w };
    __builtin_nontemporal_store(o0, (v4f*)&out[ob]);
    __builtin_nontemporal_store(o1, (v4f*)&out[ob + 4]);
}

// ---------------- diagonal blocks: out[E*64 + vtx*64 + i*8 + k] -----------
__global__ void k_diag(const float* __restrict__ dinv, float* __restrict__ out,
                       int E) {
    int idx = blockIdx.x * blockDim.x + threadIdx.x;   // float4 index in diag
    if (idx >= NN * 16) return;
    int vtx = idx >> 4;
    int rem = idx & 15;
    int i   = rem >> 1;
    int kb  = (rem & 1) * 4;
    float dv = dinv[vtx * DD + i];
    float dd = dv * dv;
    v4f o = { 0.f, 0.f, 0.f, 0.f };
    int lk = i - kb;                                    // diagonal when k==i
    if (lk >= 0 && lk < 4) o[lk] = dd;
    __builtin_nontemporal_store(o, (v4f*)out + (size_t)E * 16 + idx);
}

extern "C" void kernel_launch(void* const* d_in, const int* in_sizes, int n_in,
                              void* d_out, int out_size, void* d_ws, size_t ws_size,
                              hipStream_t stream) {
    const float* F  = (const float*)d_in[0];
    const int*   ei = (const int*)d_in[1];
    const int E = in_sizes[1] / 2;
    const int* row = ei;
    const int* col = ei + E;

    // workspace layout (~11.3 MB)
    int*   keys = (int*)d_ws;
    int*   vals = keys + HSIZE;
    int*   rev  = vals + HSIZE;
    float* deg  = (float*)(rev + E);
    float* dinv = deg + ND;
    float* out  = (float*)d_out;

    k_init<<<(HSIZE + 255) / 256, 256, 0, stream>>>(keys, vals, deg);
    k_insert<<<(E + 255) / 256, 256, 0, stream>>>(row, col, keys, vals, E);
    k_deg<<<(E + 31) / 32, 256, 0, stream>>>(F, row, col, keys, vals, rev, deg, E);
    k_dinv<<<(ND + 255) / 256, 256, 0, stream>>>(deg, dinv);
    k_pnorm<<<(E + 31) / 32, 256, 0, stream>>>(F, row, col, rev, dinv, out, E);
    k_diag<<<(NN * 16 + 255) / 256, 256, 0, stream>>>(dinv, out, E);
}

// Round 4
// 186.097 us; speedup vs baseline: 1.0818x; 1.0771x over previous
//
#include <hip/hip_runtime.h>
#include <stdint.h>

// ---------------- problem constants (from reference) ----------------
constexpr int NN   = 20000;          // N_NODES
constexpr int DD   = 8;              // D
constexpr int ND   = NN * DD;        // 160000 block-rows
constexpr uint32_t HSIZE = 1u << 20; // 1,048,576 slots for 500k keys
constexpr uint32_t HMASK = HSIZE - 1;

typedef float v4f __attribute__((ext_vector_type(4)));

__device__ __forceinline__ uint32_t hkey(uint32_t k) {
    k *= 2654435761u;
    return k ^ (k >> 15);
}

// ---------------- init: hash sentinels + deg=1 (identity contribution) ----
__global__ void k_init(int* __restrict__ keys, int* __restrict__ vals,
                       float* __restrict__ deg) {
    uint32_t i = blockIdx.x * blockDim.x + threadIdx.x;
    if (i < HSIZE) { keys[i] = -1; vals[i] = 0x7FFFFFFF; }
    if (i < (uint32_t)ND) deg[i] = 1.0f;
}

// ---------------- insert edges: key = row*NN+col, val = min edge idx ------
__global__ void k_insert(const int* __restrict__ row, const int* __restrict__ col,
                         int* __restrict__ keys, int* __restrict__ vals, int E) {
    int e = blockIdx.x * blockDim.x + threadIdx.x;
    if (e >= E) return;
    int key = row[e] * NN + col[e];
    uint32_t s = hkey((uint32_t)key) & HMASK;
    while (true) {
        int prev = atomicCAS(&keys[s], -1, key);
        if (prev == -1 || prev == key) { atomicMin(&vals[s], e); return; }
        s = (s + 1) & HMASK;
    }
}

// ---------------- rev[e] = min-index edge with reversed key (or e) --------
__global__ void k_rev(const int* __restrict__ row, const int* __restrict__ col,
                      const int* __restrict__ keys, const int* __restrict__ vals,
                      int* __restrict__ rev, int E) {
    int e = blockIdx.x * blockDim.x + threadIdx.x;
    if (e >= E) return;
    int key = col[e] * NN + row[e];
    uint32_t s = hkey((uint32_t)key) & HMASK;
    int rv = e;                          // identity fallback (matches searchsorted miss)
    while (true) {
        int k = keys[s];
        if (k == key) { rv = vals[s]; break; }
        if (k == -1) break;
        s = (s + 1) & HMASK;
    }
    rev[e] = rv;
}

// ---------------- classify: task[e] = f | cls<<29 -------------------------
// cls: 0 = skip (partner handles), 1 = standalone, 2 = pair-canonical
__global__ void k_cls(const int* __restrict__ rev, int* __restrict__ task, int E) {
    int e = blockIdx.x * blockDim.x + threadIdx.x;
    if (e >= E) return;
    int f = rev[e];
    int cls;
    if (f == e) cls = 1;                       // self / missing reverse
    else {
        int rf = rev[f];                        // gather (2 MB, L2-resident)
        cls = (rf == e) ? ((e < f) ? 2 : 0) : 1;
    }
    task[e] = f | (cls << 29);
}

// ---------------- pass A: deg accumulation (pairs counted once) -----------
// 256 threads / 32 edges per block, 8 threads per edge.
__global__ void __launch_bounds__(256)
k_deg(const float* __restrict__ F,
      const int* __restrict__ row, const int* __restrict__ col,
      const int* __restrict__ task, float* __restrict__ deg, int E) {
    __shared__ float fa[32 * 68];
    __shared__ float fb[32 * 68];
    __shared__ int s_f[32], s_cls[32], s_row[32], s_col[32];
    const int t  = threadIdx.x;
    const int e0 = blockIdx.x * 32;

    if (t < 32) {
        int e = e0 + t;
        int cls = 0, f = 0;
        if (e < E) {
            int w = task[e];
            cls = w >> 29;
            f   = w & ((1 << 29) - 1);
            s_row[t] = row[e];
            s_col[t] = col[e];
        }
        s_cls[t] = cls;
        s_f[t]   = f;
    }
    __syncthreads();

    const float4* F4 = (const float4*)F;
    #pragma unroll
    for (int p = 0; p < 2; ++p) {
        int q = t + p * 256, es = q >> 4, sub = q & 15, off = sub << 2;
        int ge = e0 + es;
        if (ge < E && s_cls[es]) {
            *(float4*)&fa[es * 68 + off] = F4[(size_t)ge * 16 + sub];
            *(float4*)&fb[es * 68 + off] = F4[(size_t)s_f[es] * 16 + sub];
        }
    }
    __syncthreads();

    const int es = t >> 3, i = t & 7, e = e0 + es;
    if (e >= E) return;
    const int cls = s_cls[es];
    if (!cls) return;

    const float* fav = &fa[es * 68];
    const float* fbv = &fb[es * 68];
    float acc0 = 0.f, acc1 = 0.f, acc2 = 0.f, acc3 = 0.f;
    float acc4 = 0.f, acc5 = 0.f, acc6 = 0.f, acc7 = 0.f;
    #pragma unroll
    for (int j = 0; j < 8; ++j) {
        float  a  = fav[j * 8 + i];
        float4 b0 = *(const float4*)&fbv[j * 8];
        float4 b1 = *(const float4*)&fbv[j * 8 + 4];
        acc0 = fmaf(a, b0.x, acc0);  acc1 = fmaf(a, b0.y, acc1);
        acc2 = fmaf(a, b0.z, acc2);  acc3 = fmaf(a, b0.w, acc3);
        acc4 = fmaf(a, b1.x, acc4);  acc5 = fmaf(a, b1.y, acc5);
        acc6 = fmaf(a, b1.z, acc6);  acc7 = fmaf(a, b1.w, acc7);
    }
    float b0 = fabsf(acc0), b1 = fabsf(acc1), b2 = fabsf(acc2), b3 = fabsf(acc3);
    float b4 = fabsf(acc4), b5 = fabsf(acc5), b6 = fabsf(acc6), b7 = fabsf(acc7);
    float rs = b0 + b1 + b2 + b3 + b4 + b5 + b6 + b7;
    atomicAdd(&deg[s_row[es] * DD + i], rs);        // rowsum |P_e| -> deg[row]

    if (cls == 2) {
        // colsum_k |P| = rowsum_k |P_f|; 8-lane butterfly (lanes share edge)
        #pragma unroll
        for (int m = 1; m < 8; m <<= 1) {
            b0 += __shfl_xor(b0, m);  b1 += __shfl_xor(b1, m);
            b2 += __shfl_xor(b2, m);  b3 += __shfl_xor(b3, m);
            b4 += __shfl_xor(b4, m);  b5 += __shfl_xor(b5, m);
            b6 += __shfl_xor(b6, m);  b7 += __shfl_xor(b7, m);
        }
        float ci = (i & 4) ? ((i & 2) ? ((i & 1) ? b7 : b6) : ((i & 1) ? b5 : b4))
                           : ((i & 2) ? ((i & 1) ? b3 : b2) : ((i & 1) ? b1 : b0));
        atomicAdd(&deg[s_col[es] * DD + i], ci);    // rowsum |P_f| -> deg[col]
    }
}

// ---------------- dinv = deg^-0.5 (deg >= 1 always) -----------------------
__global__ void k_dinv(const float* __restrict__ deg, float* __restrict__ dinv) {
    int r = blockIdx.x * blockDim.x + threadIdx.x;
    if (r < ND) dinv[r] = 1.0f / sqrtf(deg[r]);
}

// ---------------- pass B: recompute P, write normalized e and f=transpose -
__global__ void __launch_bounds__(256)
k_pnorm(const float* __restrict__ F,
        const int* __restrict__ row, const int* __restrict__ col,
        const int* __restrict__ task, const float* __restrict__ dinv,
        float* __restrict__ out, int E) {
    __shared__ float fa[32 * 68];
    __shared__ float fb[32 * 68];
    __shared__ int s_f[32], s_cls[32], s_row[32], s_col[32];
    const int t  = threadIdx.x;
    const int e0 = blockIdx.x * 32;

    if (t < 32) {
        int e = e0 + t;
        int cls = 0, f = 0;
        if (e < E) {
            int w = task[e];
            cls = w >> 29;
            f   = w & ((1 << 29) - 1);
            s_row[t] = row[e];
            s_col[t] = col[e];
        }
        s_cls[t] = cls;
        s_f[t]   = f;
    }
    __syncthreads();

    const float4* F4 = (const float4*)F;
    #pragma unroll
    for (int p = 0; p < 2; ++p) {
        int q = t + p * 256, es = q >> 4, sub = q & 15, off = sub << 2;
        int ge = e0 + es;
        if (ge < E && s_cls[es]) {
            *(float4*)&fa[es * 68 + off] = F4[(size_t)ge * 16 + sub];
            *(float4*)&fb[es * 68 + off] = F4[(size_t)s_f[es] * 16 + sub];
        }
    }
    __syncthreads();

    const int es = t >> 3, i = t & 7, e = e0 + es;
    if (e >= E) return;
    const int cls = s_cls[es];
    if (!cls) return;

    const float* fav = &fa[es * 68];
    const float* fbv = &fb[es * 68];
    float acc0 = 0.f, acc1 = 0.f, acc2 = 0.f, acc3 = 0.f;
    float acc4 = 0.f, acc5 = 0.f, acc6 = 0.f, acc7 = 0.f;
    #pragma unroll
    for (int j = 0; j < 8; ++j) {
        float  a  = fav[j * 8 + i];
        float4 b0 = *(const float4*)&fbv[j * 8];
        float4 b1 = *(const float4*)&fbv[j * 8 + 4];
        acc0 = fmaf(a, b0.x, acc0);  acc1 = fmaf(a, b0.y, acc1);
        acc2 = fmaf(a, b0.z, acc2);  acc3 = fmaf(a, b0.w, acc3);
        acc4 = fmaf(a, b1.x, acc4);  acc5 = fmaf(a, b1.y, acc5);
        acc6 = fmaf(a, b1.z, acc6);  acc7 = fmaf(a, b1.w, acc7);
    }

    const int r = s_row[es], c = s_col[es];
    float dr  = dinv[r * DD + i];
    v4f  dc0  = *(const v4f*)&dinv[c * DD];
    v4f  dc1  = *(const v4f*)&dinv[c * DD + 4];

    float v[8];
    v[0] = acc0 * dr * dc0.x;  v[1] = acc1 * dr * dc0.y;
    v[2] = acc2 * dr * dc0.z;  v[3] = acc3 * dr * dc0.w;
    v[4] = acc4 * dr * dc1.x;  v[5] = acc5 * dr * dc1.y;
    v[6] = acc6 * dr * dc1.z;  v[7] = acc7 * dr * dc1.w;

    v4f w0 = { v[0], v[1], v[2], v[3] };
    v4f w1 = { v[4], v[5], v[6], v[7] };
    size_t ob = (size_t)e * 64 + i * 8;
    __builtin_nontemporal_store(w0, (v4f*)&out[ob]);
    __builtin_nontemporal_store(w1, (v4f*)&out[ob + 4]);

    if (cls == 2) {
        // out[f] = transpose(out[e]) exactly (normalization is symmetric).
        // Register 8x8 transpose across the edge's 8 lanes: swap bit m
        // between lane index and slot index, m = 1,2,4. All slot indices
        // compile-time (rule #20).
        #pragma unroll
        for (int m = 1; m < 8; m <<= 1) {
            #pragma unroll
            for (int j = 0; j < 8; ++j) {
                if ((j & m) == 0) {
                    float sel = (i & m) ? v[j] : v[j | m];
                    float got = __shfl_xor(sel, m);
                    float nj  = (i & m) ? got : v[j];
                    float njm = (i & m) ? v[j | m] : got;
                    v[j] = nj;  v[j | m] = njm;
                }
            }
        }
        v4f u0 = { v[0], v[1], v[2], v[3] };
        v4f u1 = { v[4], v[5], v[6], v[7] };
        size_t fb_ = (size_t)s_f[es] * 64 + i * 8;
        __builtin_nontemporal_store(u0, (v4f*)&out[fb_]);
        __builtin_nontemporal_store(u1, (v4f*)&out[fb_ + 4]);
    }
}

// ---------------- diagonal blocks: out[E*64 + vtx*64 + i*8 + k] -----------
__global__ void k_diag(const float* __restrict__ dinv, float* __restrict__ out,
                       int E) {
    int idx = blockIdx.x * blockDim.x + threadIdx.x;   // float4 index in diag
    if (idx >= NN * 16) return;
    int vtx = idx >> 4;
    int rem = idx & 15;
    int i   = rem >> 1;
    int kb  = (rem & 1) * 4;
    float dv = dinv[vtx * DD + i];
    float dd = dv * dv;
    v4f o = { 0.f, 0.f, 0.f, 0.f };
    int lk = i - kb;                                    // diagonal when k==i
    if (lk >= 0 && lk < 4) o[lk] = dd;
    __builtin_nontemporal_store(o, (v4f*)out + (size_t)E * 16 + idx);
}

extern "C" void kernel_launch(void* const* d_in, const int* in_sizes, int n_in,
                              void* d_out, int out_size, void* d_ws, size_t ws_size,
                              hipStream_t stream) {
    const float* F  = (const float*)d_in[0];
    const int*   ei = (const int*)d_in[1];
    const int E = in_sizes[1] / 2;
    const int* row = ei;
    const int* col = ei + E;

    // workspace layout (~13.3 MB)
    int*   keys = (int*)d_ws;
    int*   vals = keys + HSIZE;
    int*   rev  = vals + HSIZE;
    int*   task = rev + E;
    float* deg  = (float*)(task + E);
    float* dinv = deg + ND;
    float* out  = (float*)d_out;

    k_init  <<<(HSIZE + 255) / 256, 256, 0, stream>>>(keys, vals, deg);
    k_insert<<<(E + 255) / 256,     256, 0, stream>>>(row, col, keys, vals, E);
    k_rev   <<<(E + 255) / 256,     256, 0, stream>>>(row, col, keys, vals, rev, E);
    k_cls   <<<(E + 255) / 256,     256, 0, stream>>>(rev, task, E);
    k_deg   <<<(E + 31) / 32,       256, 0, stream>>>(F, row, col, task, deg, E);
    k_dinv  <<<(ND + 255) / 256,    256, 0, stream>>>(deg, dinv);
    k_pnorm <<<(E + 31) / 32,       256, 0, stream>>>(F, row, col, task, dinv, out, E);
    k_diag  <<<(NN * 16 + 255) / 256, 256, 0, stream>>>(dinv, out, E);
}

// Round 5
// 157.373 us; speedup vs baseline: 1.2792x; 1.1825x over previous
//
#include <hip/hip_runtime.h>
#include <stdint.h>

// ---------------- problem constants (from reference) ----------------
constexpr int NN   = 20000;          // N_NODES
constexpr int DD   = 8;              // D
constexpr int ND   = NN * DD;        // 160000 block-rows
constexpr uint32_t HSIZE = 1u << 20; // 1,048,576 slots for 500k keys
constexpr uint32_t HMASK = HSIZE - 1;
// packed slot: (key << 19) | edge_idx.  key < 2^29, idx < 2^19. EMPTY = all-ones.
constexpr unsigned long long EMPTY64 = ~0ULL;

typedef float v4f __attribute__((ext_vector_type(4)));

__device__ __forceinline__ uint32_t hkey(uint32_t k) {
    k *= 2654435761u;
    return k ^ (k >> 15);
}

// ---------------- deg = 1 (identity contribution) -------------------------
__global__ void k_init(float* __restrict__ deg) {
    uint32_t i = blockIdx.x * blockDim.x + threadIdx.x;
    if (i < (uint32_t)ND) deg[i] = 1.0f;
}

// ---------------- insert: single fused atomicMin64 per probe --------------
// Robin-Hood linear probing: slot only decreases; displaced (larger) entries
// are carried rightward. Same-key entries collapse to min edge idx, which is
// exactly the reference's stable argsort+searchsorted semantics.
__global__ void k_insert(const int* __restrict__ row, const int* __restrict__ col,
                         unsigned long long* __restrict__ slots, int E) {
    int e = blockIdx.x * blockDim.x + threadIdx.x;
    if (e >= E) return;
    uint32_t key = (uint32_t)(row[e] * NN + col[e]);
    unsigned long long cur = ((unsigned long long)key << 19) | (unsigned)e;
    uint32_t s = hkey(key) & HMASK;
    while (true) {
        unsigned long long old = atomicMin(&slots[s], cur);
        if (old == EMPTY64) break;                           // claimed empty slot
        if ((uint32_t)(old >> 19) == key) break;             // same key: min kept
        if (old > cur) { cur = old; key = (uint32_t)(cur >> 19); } // displaced it
        s = (s + 1) & HMASK;
    }
}

// ---------------- rev[e] = min-index edge with reversed key (or e) --------
__global__ void k_rev(const int* __restrict__ row, const int* __restrict__ col,
                      const unsigned long long* __restrict__ slots,
                      int* __restrict__ rev, int E) {
    int e = blockIdx.x * blockDim.x + threadIdx.x;
    if (e >= E) return;
    uint32_t key = (uint32_t)(col[e] * NN + row[e]);
    uint32_t s = hkey(key) & HMASK;
    int rv = e;                       // identity fallback (searchsorted miss)
    while (true) {
        unsigned long long v = slots[s];
        if (v == EMPTY64) break;
        if ((uint32_t)(v >> 19) == key) { rv = (int)(v & 0x7FFFFu); break; }
        s = (s + 1) & HMASK;
    }
    rev[e] = rv;
}

// ---------------- classify: task[e] = f | cls<<29 -------------------------
// cls: 0 = skip (partner handles), 1 = standalone, 2 = pair-canonical
__global__ void k_cls(const int* __restrict__ rev, int* __restrict__ task, int E) {
    int e = blockIdx.x * blockDim.x + threadIdx.x;
    if (e >= E) return;
    int f = rev[e];
    int cls;
    if (f == e) cls = 1;                       // self / missing reverse
    else {
        int rf = rev[f];                        // gather (2 MB, L2-resident)
        cls = (rf == e) ? ((e < f) ? 2 : 0) : 1;
    }
    task[e] = f | (cls << 29);
}

// ---------------- pass A: deg accumulation (pairs counted once) -----------
// 256 threads / 32 edges per block, 8 threads per edge.
__global__ void __launch_bounds__(256)
k_deg(const float* __restrict__ F,
      const int* __restrict__ row, const int* __restrict__ col,
      const int* __restrict__ task, float* __restrict__ deg, int E) {
    __shared__ float fa[32 * 68];
    __shared__ float fb[32 * 68];
    __shared__ int s_f[32], s_cls[32], s_row[32], s_col[32];
    const int t  = threadIdx.x;
    const int e0 = blockIdx.x * 32;

    if (t < 32) {
        int e = e0 + t;
        int cls = 0, f = 0;
        if (e < E) {
            int w = task[e];
            cls = w >> 29;
            f   = w & ((1 << 29) - 1);
            s_row[t] = row[e];
            s_col[t] = col[e];
        }
        s_cls[t] = cls;
        s_f[t]   = f;
    }
    __syncthreads();

    const float4* F4 = (const float4*)F;
    #pragma unroll
    for (int p = 0; p < 2; ++p) {
        int q = t + p * 256, es = q >> 4, sub = q & 15, off = sub << 2;
        int ge = e0 + es;
        if (ge < E && s_cls[es]) {
            *(float4*)&fa[es * 68 + off] = F4[(size_t)ge * 16 + sub];
            *(float4*)&fb[es * 68 + off] = F4[(size_t)s_f[es] * 16 + sub];
        }
    }
    __syncthreads();

    const int es = t >> 3, i = t & 7, e = e0 + es;
    if (e >= E) return;
    const int cls = s_cls[es];
    if (!cls) return;

    const float* fav = &fa[es * 68];
    const float* fbv = &fb[es * 68];
    float acc0 = 0.f, acc1 = 0.f, acc2 = 0.f, acc3 = 0.f;
    float acc4 = 0.f, acc5 = 0.f, acc6 = 0.f, acc7 = 0.f;
    #pragma unroll
    for (int j = 0; j < 8; ++j) {
        float  a  = fav[j * 8 + i];
        float4 b0 = *(const float4*)&fbv[j * 8];
        float4 b1 = *(const float4*)&fbv[j * 8 + 4];
        acc0 = fmaf(a, b0.x, acc0);  acc1 = fmaf(a, b0.y, acc1);
        acc2 = fmaf(a, b0.z, acc2);  acc3 = fmaf(a, b0.w, acc3);
        acc4 = fmaf(a, b1.x, acc4);  acc5 = fmaf(a, b1.y, acc5);
        acc6 = fmaf(a, b1.z, acc6);  acc7 = fmaf(a, b1.w, acc7);
    }
    float b0 = fabsf(acc0), b1 = fabsf(acc1), b2 = fabsf(acc2), b3 = fabsf(acc3);
    float b4 = fabsf(acc4), b5 = fabsf(acc5), b6 = fabsf(acc6), b7 = fabsf(acc7);
    float rs = b0 + b1 + b2 + b3 + b4 + b5 + b6 + b7;
    atomicAdd(&deg[s_row[es] * DD + i], rs);        // rowsum |P_e| -> deg[row]

    if (cls == 2) {
        // colsum_k |P| = rowsum_k |P_f|; 8-lane butterfly (lanes share edge)
        #pragma unroll
        for (int m = 1; m < 8; m <<= 1) {
            b0 += __shfl_xor(b0, m);  b1 += __shfl_xor(b1, m);
            b2 += __shfl_xor(b2, m);  b3 += __shfl_xor(b3, m);
            b4 += __shfl_xor(b4, m);  b5 += __shfl_xor(b5, m);
            b6 += __shfl_xor(b6, m);  b7 += __shfl_xor(b7, m);
        }
        float ci = (i & 4) ? ((i & 2) ? ((i & 1) ? b7 : b6) : ((i & 1) ? b5 : b4))
                           : ((i & 2) ? ((i & 1) ? b3 : b2) : ((i & 1) ? b1 : b0));
        atomicAdd(&deg[s_col[es] * DD + i], ci);    // rowsum |P_f| -> deg[col]
    }
}

// ---------------- dinv = deg^-0.5 (deg >= 1 always) -----------------------
__global__ void k_dinv(const float* __restrict__ deg, float* __restrict__ dinv) {
    int r = blockIdx.x * blockDim.x + threadIdx.x;
    if (r < ND) dinv[r] = 1.0f / sqrtf(deg[r]);
}

// ---------------- pass B: recompute P, write normalized e and f=transpose -
__global__ void __launch_bounds__(256)
k_pnorm(const float* __restrict__ F,
        const int* __restrict__ row, const int* __restrict__ col,
        const int* __restrict__ task, const float* __restrict__ dinv,
        float* __restrict__ out, int E) {
    __shared__ float fa[32 * 68];
    __shared__ float fb[32 * 68];
    __shared__ int s_f[32], s_cls[32], s_row[32], s_col[32];
    const int t  = threadIdx.x;
    const int e0 = blockIdx.x * 32;

    if (t < 32) {
        int e = e0 + t;
        int cls = 0, f = 0;
        if (e < E) {
            int w = task[e];
            cls = w >> 29;
            f   = w & ((1 << 29) - 1);
            s_row[t] = row[e];
            s_col[t] = col[e];
        }
        s_cls[t] = cls;
        s_f[t]   = f;
    }
    __syncthreads();

    const float4* F4 = (const float4*)F;
    #pragma unroll
    for (int p = 0; p < 2; ++p) {
        int q = t + p * 256, es = q >> 4, sub = q & 15, off = sub << 2;
        int ge = e0 + es;
        if (ge < E && s_cls[es]) {
            *(float4*)&fa[es * 68 + off] = F4[(size_t)ge * 16 + sub];
            *(float4*)&fb[es * 68 + off] = F4[(size_t)s_f[es] * 16 + sub];
        }
    }
    __syncthreads();

    const int es = t >> 3, i = t & 7, e = e0 + es;
    if (e >= E) return;
    const int cls = s_cls[es];
    if (!cls) return;

    const float* fav = &fa[es * 68];
    const float* fbv = &fb[es * 68];
    float acc0 = 0.f, acc1 = 0.f, acc2 = 0.f, acc3 = 0.f;
    float acc4 = 0.f, acc5 = 0.f, acc6 = 0.f, acc7 = 0.f;
    #pragma unroll
    for (int j = 0; j < 8; ++j) {
        float  a  = fav[j * 8 + i];
        float4 b0 = *(const float4*)&fbv[j * 8];
        float4 b1 = *(const float4*)&fbv[j * 8 + 4];
        acc0 = fmaf(a, b0.x, acc0);  acc1 = fmaf(a, b0.y, acc1);
        acc2 = fmaf(a, b0.z, acc2);  acc3 = fmaf(a, b0.w, acc3);
        acc4 = fmaf(a, b1.x, acc4);  acc5 = fmaf(a, b1.y, acc5);
        acc6 = fmaf(a, b1.z, acc6);  acc7 = fmaf(a, b1.w, acc7);
    }

    const int r = s_row[es], c = s_col[es];
    float dr  = dinv[r * DD + i];
    v4f  dc0  = *(const v4f*)&dinv[c * DD];
    v4f  dc1  = *(const v4f*)&dinv[c * DD + 4];

    float v[8];
    v[0] = acc0 * dr * dc0.x;  v[1] = acc1 * dr * dc0.y;
    v[2] = acc2 * dr * dc0.z;  v[3] = acc3 * dr * dc0.w;
    v[4] = acc4 * dr * dc1.x;  v[5] = acc5 * dr * dc1.y;
    v[6] = acc6 * dr * dc1.z;  v[7] = acc7 * dr * dc1.w;

    v4f w0 = { v[0], v[1], v[2], v[3] };
    v4f w1 = { v[4], v[5], v[6], v[7] };
    size_t ob = (size_t)e * 64 + i * 8;
    __builtin_nontemporal_store(w0, (v4f*)&out[ob]);
    __builtin_nontemporal_store(w1, (v4f*)&out[ob + 4]);

    if (cls == 2) {
        // out[f] = transpose(out[e]) exactly (normalization is symmetric).
        // Register 8x8 transpose across the edge's 8 lanes (compile-time
        // slot indices only — rule #20).
        #pragma unroll
        for (int m = 1; m < 8; m <<= 1) {
            #pragma unroll
            for (int j = 0; j < 8; ++j) {
                if ((j & m) == 0) {
                    float sel = (i & m) ? v[j] : v[j | m];
                    float got = __shfl_xor(sel, m);
                    float nj  = (i & m) ? got : v[j];
                    float njm = (i & m) ? v[j | m] : got;
                    v[j] = nj;  v[j | m] = njm;
                }
            }
        }
        v4f u0 = { v[0], v[1], v[2], v[3] };
        v4f u1 = { v[4], v[5], v[6], v[7] };
        size_t fb_ = (size_t)s_f[es] * 64 + i * 8;
        __builtin_nontemporal_store(u0, (v4f*)&out[fb_]);
        __builtin_nontemporal_store(u1, (v4f*)&out[fb_ + 4]);
    }
}

// ---------------- diagonal blocks: out[E*64 + vtx*64 + i*8 + k] -----------
__global__ void k_diag(const float* __restrict__ dinv, float* __restrict__ out,
                       int E) {
    int idx = blockIdx.x * blockDim.x + threadIdx.x;   // float4 index in diag
    if (idx >= NN * 16) return;
    int vtx = idx >> 4;
    int rem = idx & 15;
    int i   = rem >> 1;
    int kb  = (rem & 1) * 4;
    float dv = dinv[vtx * DD + i];
    float dd = dv * dv;
    v4f o = { 0.f, 0.f, 0.f, 0.f };
    int lk = i - kb;                                    // diagonal when k==i
    if (lk >= 0 && lk < 4) o[lk] = dd;
    __builtin_nontemporal_store(o, (v4f*)out + (size_t)E * 16 + idx);
}

extern "C" void kernel_launch(void* const* d_in, const int* in_sizes, int n_in,
                              void* d_out, int out_size, void* d_ws, size_t ws_size,
                              hipStream_t stream) {
    const float* F  = (const float*)d_in[0];
    const int*   ei = (const int*)d_in[1];
    const int E = in_sizes[1] / 2;
    const int* row = ei;
    const int* col = ei + E;

    // workspace layout (~13.9 MB)
    unsigned long long* slots = (unsigned long long*)d_ws;          // 8 MB
    int*   rev  = (int*)(slots + HSIZE);
    int*   task = rev + E;
    float* deg  = (float*)(task + E);
    float* dinv = deg + ND;
    float* out  = (float*)d_out;

    hipMemsetAsync(slots, 0xFF, HSIZE * sizeof(unsigned long long), stream);
    k_init  <<<(ND + 255) / 256,    256, 0, stream>>>(deg);
    k_insert<<<(E + 255) / 256,     256, 0, stream>>>(row, col, slots, E);
    k_rev   <<<(E + 255) / 256,     256, 0, stream>>>(row, col, slots, rev, E);
    k_cls   <<<(E + 255) / 256,     256, 0, stream>>>(rev, task, E);
    k_deg   <<<(E + 31) / 32,       256, 0, stream>>>(F, row, col, task, deg, E);
    k_dinv  <<<(ND + 255) / 256,    256, 0, stream>>>(deg, dinv);
    k_pnorm <<<(E + 31) / 32,       256, 0, stream>>>(F, row, col, task, dinv, out, E);
    k_diag  <<<(NN * 16 + 255) / 256, 256, 0, stream>>>(dinv, out, E);
}

// Round 6
// 156.002 us; speedup vs baseline: 1.2904x; 1.0088x over previous
//
#include <hip/hip_runtime.h>
#include <stdint.h>

// ---------------- problem constants (from reference) ----------------
constexpr int NN   = 20000;          // N_NODES
constexpr int DD   = 8;              // D
constexpr int ND   = NN * DD;        // 160000 block-rows
constexpr uint32_t HSIZE = 1u << 20; // 1,048,576 slots for 500k keys
constexpr uint32_t HMASK = HSIZE - 1;
// packed slot: (key << 19) | edge_idx.  key < 2^29, idx < 2^19. EMPTY = all-ones.
constexpr unsigned long long EMPTY64 = ~0ULL;

typedef float v4f __attribute__((ext_vector_type(4)));

__device__ __forceinline__ uint32_t hkey(uint32_t k) {
    k *= 2654435761u;
    return k ^ (k >> 15);
}

// ---------------- fused fill: slots = EMPTY (16B stores) + deg = 1 --------
// 524288 threads: one ulonglong2 store each covers the 8 MB table at HBM
// rate (~3 µs) instead of the runtime's 109 GB/s fillBufferAligned (76 µs).
__global__ void k_fill(unsigned long long* __restrict__ slots,
                       float* __restrict__ deg) {
    uint32_t i = blockIdx.x * blockDim.x + threadIdx.x;
    if (i < HSIZE / 2) {
        ulonglong2 v; v.x = EMPTY64; v.y = EMPTY64;
        ((ulonglong2*)slots)[i] = v;
    }
    if (i < (uint32_t)ND) deg[i] = 1.0f;
}

// ---------------- insert: single fused atomicMin64 per probe --------------
// Robin-Hood linear probing: slot only decreases; displaced (larger) entries
// are carried rightward. Same-key entries collapse to min edge idx, which is
// exactly the reference's stable argsort+searchsorted semantics.
__global__ void k_insert(const int* __restrict__ row, const int* __restrict__ col,
                         unsigned long long* __restrict__ slots, int E) {
    int e = blockIdx.x * blockDim.x + threadIdx.x;
    if (e >= E) return;
    uint32_t key = (uint32_t)(row[e] * NN + col[e]);
    unsigned long long cur = ((unsigned long long)key << 19) | (unsigned)e;
    uint32_t s = hkey(key) & HMASK;
    while (true) {
        unsigned long long old = atomicMin(&slots[s], cur);
        if (old == EMPTY64) break;                           // claimed empty slot
        if ((uint32_t)(old >> 19) == key) break;             // same key: min kept
        if (old > cur) { cur = old; key = (uint32_t)(cur >> 19); } // displaced it
        s = (s + 1) & HMASK;
    }
}

// ---------------- rev[e] = min-index edge with reversed key (or e) --------
__global__ void k_rev(const int* __restrict__ row, const int* __restrict__ col,
                      const unsigned long long* __restrict__ slots,
                      int* __restrict__ rev, int E) {
    int e = blockIdx.x * blockDim.x + threadIdx.x;
    if (e >= E) return;
    uint32_t key = (uint32_t)(col[e] * NN + row[e]);
    uint32_t s = hkey(key) & HMASK;
    int rv = e;                       // identity fallback (searchsorted miss)
    while (true) {
        unsigned long long v = slots[s];
        if (v == EMPTY64) break;
        if ((uint32_t)(v >> 19) == key) { rv = (int)(v & 0x7FFFFu); break; }
        s = (s + 1) & HMASK;
    }
    rev[e] = rv;
}

// ---------------- classify: task[e] = f | cls<<29 -------------------------
// cls: 0 = skip (partner handles), 1 = standalone, 2 = pair-canonical
__global__ void k_cls(const int* __restrict__ rev, int* __restrict__ task, int E) {
    int e = blockIdx.x * blockDim.x + threadIdx.x;
    if (e >= E) return;
    int f = rev[e];
    int cls;
    if (f == e) cls = 1;                       // self / missing reverse
    else {
        int rf = rev[f];                        // gather (2 MB, L2-resident)
        cls = (rf == e) ? ((e < f) ? 2 : 0) : 1;
    }
    task[e] = f | (cls << 29);
}

// ---------------- pass A: deg accumulation (pairs counted once) -----------
// 256 threads / 32 edges per block, 8 threads per edge.
__global__ void __launch_bounds__(256)
k_deg(const float* __restrict__ F,
      const int* __restrict__ row, const int* __restrict__ col,
      const int* __restrict__ task, float* __restrict__ deg, int E) {
    __shared__ float fa[32 * 68];
    __shared__ float fb[32 * 68];
    __shared__ int s_f[32], s_cls[32], s_row[32], s_col[32];
    const int t  = threadIdx.x;
    const int e0 = blockIdx.x * 32;

    if (t < 32) {
        int e = e0 + t;
        int cls = 0, f = 0;
        if (e < E) {
            int w = task[e];
            cls = w >> 29;
            f   = w & ((1 << 29) - 1);
            s_row[t] = row[e];
            s_col[t] = col[e];
        }
        s_cls[t] = cls;
        s_f[t]   = f;
    }
    __syncthreads();

    const float4* F4 = (const float4*)F;
    #pragma unroll
    for (int p = 0; p < 2; ++p) {
        int q = t + p * 256, es = q >> 4, sub = q & 15, off = sub << 2;
        int ge = e0 + es;
        if (ge < E && s_cls[es]) {
            *(float4*)&fa[es * 68 + off] = F4[(size_t)ge * 16 + sub];
            *(float4*)&fb[es * 68 + off] = F4[(size_t)s_f[es] * 16 + sub];
        }
    }
    __syncthreads();

    const int es = t >> 3, i = t & 7, e = e0 + es;
    if (e >= E) return;
    const int cls = s_cls[es];
    if (!cls) return;

    const float* fav = &fa[es * 68];
    const float* fbv = &fb[es * 68];
    float acc0 = 0.f, acc1 = 0.f, acc2 = 0.f, acc3 = 0.f;
    float acc4 = 0.f, acc5 = 0.f, acc6 = 0.f, acc7 = 0.f;
    #pragma unroll
    for (int j = 0; j < 8; ++j) {
        float  a  = fav[j * 8 + i];
        float4 b0 = *(const float4*)&fbv[j * 8];
        float4 b1 = *(const float4*)&fbv[j * 8 + 4];
        acc0 = fmaf(a, b0.x, acc0);  acc1 = fmaf(a, b0.y, acc1);
        acc2 = fmaf(a, b0.z, acc2);  acc3 = fmaf(a, b0.w, acc3);
        acc4 = fmaf(a, b1.x, acc4);  acc5 = fmaf(a, b1.y, acc5);
        acc6 = fmaf(a, b1.z, acc6);  acc7 = fmaf(a, b1.w, acc7);
    }
    float b0 = fabsf(acc0), b1 = fabsf(acc1), b2 = fabsf(acc2), b3 = fabsf(acc3);
    float b4 = fabsf(acc4), b5 = fabsf(acc5), b6 = fabsf(acc6), b7 = fabsf(acc7);
    float rs = b0 + b1 + b2 + b3 + b4 + b5 + b6 + b7;
    atomicAdd(&deg[s_row[es] * DD + i], rs);        // rowsum |P_e| -> deg[row]

    if (cls == 2) {
        // colsum_k |P| = rowsum_k |P_f|; 8-lane butterfly (lanes share edge)
        #pragma unroll
        for (int m = 1; m < 8; m <<= 1) {
            b0 += __shfl_xor(b0, m);  b1 += __shfl_xor(b1, m);
            b2 += __shfl_xor(b2, m);  b3 += __shfl_xor(b3, m);
            b4 += __shfl_xor(b4, m);  b5 += __shfl_xor(b5, m);
            b6 += __shfl_xor(b6, m);  b7 += __shfl_xor(b7, m);
        }
        float ci = (i & 4) ? ((i & 2) ? ((i & 1) ? b7 : b6) : ((i & 1) ? b5 : b4))
                           : ((i & 2) ? ((i & 1) ? b3 : b2) : ((i & 1) ? b1 : b0));
        atomicAdd(&deg[s_col[es] * DD + i], ci);    // rowsum |P_f| -> deg[col]
    }
}

// ---------------- dinv = deg^-0.5 (deg >= 1 always) -----------------------
__global__ void k_dinv(const float* __restrict__ deg, float* __restrict__ dinv) {
    int r = blockIdx.x * blockDim.x + threadIdx.x;
    if (r < ND) dinv[r] = 1.0f / sqrtf(deg[r]);
}

// ---------------- pass B: recompute P, write normalized e and f=transpose -
__global__ void __launch_bounds__(256)
k_pnorm(const float* __restrict__ F,
        const int* __restrict__ row, const int* __restrict__ col,
        const int* __restrict__ task, const float* __restrict__ dinv,
        float* __restrict__ out, int E) {
    __shared__ float fa[32 * 68];
    __shared__ float fb[32 * 68];
    __shared__ int s_f[32], s_cls[32], s_row[32], s_col[32];
    const int t  = threadIdx.x;
    const int e0 = blockIdx.x * 32;

    if (t < 32) {
        int e = e0 + t;
        int cls = 0, f = 0;
        if (e < E) {
            int w = task[e];
            cls = w >> 29;
            f   = w & ((1 << 29) - 1);
            s_row[t] = row[e];
            s_col[t] = col[e];
        }
        s_cls[t] = cls;
        s_f[t]   = f;
    }
    __syncthreads();

    const float4* F4 = (const float4*)F;
    #pragma unroll
    for (int p = 0; p < 2; ++p) {
        int q = t + p * 256, es = q >> 4, sub = q & 15, off = sub << 2;
        int ge = e0 + es;
        if (ge < E && s_cls[es]) {
            *(float4*)&fa[es * 68 + off] = F4[(size_t)ge * 16 + sub];
            *(float4*)&fb[es * 68 + off] = F4[(size_t)s_f[es] * 16 + sub];
        }
    }
    __syncthreads();

    const int es = t >> 3, i = t & 7, e = e0 + es;
    if (e >= E) return;
    const int cls = s_cls[es];
    if (!cls) return;

    const float* fav = &fa[es * 68];
    const float* fbv = &fb[es * 68];
    float acc0 = 0.f, acc1 = 0.f, acc2 = 0.f, acc3 = 0.f;
    float acc4 = 0.f, acc5 = 0.f, acc6 = 0.f, acc7 = 0.f;
    #pragma unroll
    for (int j = 0; j < 8; ++j) {
        float  a  = fav[j * 8 + i];
        float4 b0 = *(const float4*)&fbv[j * 8];
        float4 b1 = *(const float4*)&fbv[j * 8 + 4];
        acc0 = fmaf(a, b0.x, acc0);  acc1 = fmaf(a, b0.y, acc1);
        acc2 = fmaf(a, b0.z, acc2);  acc3 = fmaf(a, b0.w, acc3);
        acc4 = fmaf(a, b1.x, acc4);  acc5 = fmaf(a, b1.y, acc5);
        acc6 = fmaf(a, b1.z, acc6);  acc7 = fmaf(a, b1.w, acc7);
    }

    const int r = s_row[es], c = s_col[es];
    float dr  = dinv[r * DD + i];
    v4f  dc0  = *(const v4f*)&dinv[c * DD];
    v4f  dc1  = *(const v4f*)&dinv[c * DD + 4];

    float v[8];
    v[0] = acc0 * dr * dc0.x;  v[1] = acc1 * dr * dc0.y;
    v[2] = acc2 * dr * dc0.z;  v[3] = acc3 * dr * dc0.w;
    v[4] = acc4 * dr * dc1.x;  v[5] = acc5 * dr * dc1.y;
    v[6] = acc6 * dr * dc1.z;  v[7] = acc7 * dr * dc1.w;

    v4f w0 = { v[0], v[1], v[2], v[3] };
    v4f w1 = { v[4], v[5], v[6], v[7] };
    size_t ob = (size_t)e * 64 + i * 8;
    __builtin_nontemporal_store(w0, (v4f*)&out[ob]);
    __builtin_nontemporal_store(w1, (v4f*)&out[ob + 4]);

    if (cls == 2) {
        // out[f] = transpose(out[e]) exactly (normalization is symmetric).
        // Register 8x8 transpose across the edge's 8 lanes (compile-time
        // slot indices only — rule #20).
        #pragma unroll
        for (int m = 1; m < 8; m <<= 1) {
            #pragma unroll
            for (int j = 0; j < 8; ++j) {
                if ((j & m) == 0) {
                    float sel = (i & m) ? v[j] : v[j | m];
                    float got = __shfl_xor(sel, m);
                    float nj  = (i & m) ? got : v[j];
                    float njm = (i & m) ? v[j | m] : got;
                    v[j] = nj;  v[j | m] = njm;
                }
            }
        }
        v4f u0 = { v[0], v[1], v[2], v[3] };
        v4f u1 = { v[4], v[5], v[6], v[7] };
        size_t fb_ = (size_t)s_f[es] * 64 + i * 8;
        __builtin_nontemporal_store(u0, (v4f*)&out[fb_]);
        __builtin_nontemporal_store(u1, (v4f*)&out[fb_ + 4]);
    }
}

// ---------------- diagonal blocks: out[E*64 + vtx*64 + i*8 + k] -----------
__global__ void k_diag(const float* __restrict__ dinv, float* __restrict__ out,
                       int E) {
    int idx = blockIdx.x * blockDim.x + threadIdx.x;   // float4 index in diag
    if (idx >= NN * 16) return;
    int vtx = idx >> 4;
    int rem = idx & 15;
    int i   = rem >> 1;
    int kb  = (rem & 1) * 4;
    float dv = dinv[vtx * DD + i];
    float dd = dv * dv;
    v4f o = { 0.f, 0.f, 0.f, 0.f };
    int lk = i - kb;                                    // diagonal when k==i
    if (lk >= 0 && lk < 4) o[lk] = dd;
    __builtin_nontemporal_store(o, (v4f*)out + (size_t)E * 16 + idx);
}

extern "C" void kernel_launch(void* const* d_in, const int* in_sizes, int n_in,
                              void* d_out, int out_size, void* d_ws, size_t ws_size,
                              hipStream_t stream) {
    const float* F  = (const float*)d_in[0];
    const int*   ei = (const int*)d_in[1];
    const int E = in_sizes[1] / 2;
    const int* row = ei;
    const int* col = ei + E;

    // workspace layout (~13.9 MB)
    unsigned long long* slots = (unsigned long long*)d_ws;          // 8 MB
    int*   rev  = (int*)(slots + HSIZE);
    int*   task = rev + E;
    float* deg  = (float*)(task + E);
    float* dinv = deg + ND;
    float* out  = (float*)d_out;

    k_fill  <<<(HSIZE / 2 + 255) / 256, 256, 0, stream>>>(slots, deg);
    k_insert<<<(E + 255) / 256,     256, 0, stream>>>(row, col, slots, E);
    k_rev   <<<(E + 255) / 256,     256, 0, stream>>>(row, col, slots, rev, E);
    k_cls   <<<(E + 255) / 256,     256, 0, stream>>>(rev, task, E);
    k_deg   <<<(E + 31) / 32,       256, 0, stream>>>(F, row, col, task, deg, E);
    k_dinv  <<<(ND + 255) / 256,    256, 0, stream>>>(deg, dinv);
    k_pnorm <<<(E + 31) / 32,       256, 0, stream>>>(F, row, col, task, dinv, out, E);
    k_diag  <<<(NN * 16 + 255) / 256, 256, 0, stream>>>(dinv, out, E);
}